// Round 5
// baseline (149.080 us; speedup 1.0000x reference)
//
#include <hip/hip_runtime.h>
#include <hip/hip_fp16.h>

#define R_ 3
#define D_ 7            // 2R+1
#define W_ 49
#define N_ 128
#define K_ 131
#define C_ 21
#define B_ 2
#define NN (N_ * N_)
#define TI_ 8                   // tile rows
#define TJ_ 16                  // tile cols
#define PROWS (TI_ + 2 * R_)    // 14
#define PCOLS (TJ_ + 2 * R_)    // 22
#define PSTR 24                 // LDS row stride (32-bit words)
#define NELEM (PROWS * PCOLS)   // 308 staged elements
#define LDSP (PROWS * PSTR + 8) // 344 words (spare write slot at 340)
#define KC 8                    // k-chunks per tile
#define KCHUNK ((K_ + KC - 1) / KC)    // 17
#define HCELLS (PROWS * PCOLS)  // 308 halo cells for gather

typedef __fp16 h2 __attribute__((ext_vector_type(2)));

static __device__ __forceinline__ unsigned h2u(h2 x) { return __builtin_bit_cast(unsigned, x); }
static __device__ __forceinline__ h2 u2h(unsigned x) { return __builtin_bit_cast(h2, x); }

#if defined(__has_builtin)
#if __has_builtin(__builtin_amdgcn_fdot2)
#define FDOT2(a, b, c) __builtin_amdgcn_fdot2((a), (b), (c), false)
#endif
#endif
#ifndef FDOT2
#define FDOT2(a, b, c) ((c) + (float)(a)[0] * (float)(b)[0] + (float)(a)[1] * (float)(b)[1])
#endif

// Affinity R5: LDS-op-throughput was co-limiting (29 ds_read_b64/wave/k ->
// ~6.9k cyc/CU/k through the one LDS pipe; R3 proved latency-hoisting is
// worthless because the pipe itself is the cost). This version halves LDS
// ops and cuts VALU by packing each staged element into ONE 32-bit word
// half2(E, 1/E), with CONTIGUOUS column ownership (h=0: v=0..3, h=1:
// v=4..7; v=7 is the phantom, killed via ph2 before denom+accum):
//  * per row u: 4 consecutive dwords -> 2x ds_read2_b32 (was 2x b64 at
//    stride 2); LDS ops/k 31 -> ~17.
//  * taps packed: v_perm deinterleave + v_pk_mul/v_pk_max; cvt_pkrtz gone
//    (taps born packed); denom via v_dot2_f32_f16 keeps f32 accumulation.
//  * precision: operands fp16-rounded before product (was f32) -> absmax
//    expected ~2-3x the prior 0.25.
// Grid/KC/barriers/prefetch/epilogue structure identical to proven R0.
__global__ __launch_bounds__(256) void rwn_affinity(
    const float* __restrict__ feats,   // [B,K,N,N]
    const int*   __restrict__ mask,    // [B,N,N]
    const float* __restrict__ cp,      // [K]
    float* __restrict__ Aout)          // [B,W,NN] (pre-zeroed)
{
    __shared__ unsigned patchw[LDSP];  // half2(E, 1/E) per halo cell

    const int tile = blockIdx.x;           // 0..127 (16x8 tiles of 8x16)
    const int kc   = blockIdx.y;
    const int b    = blockIdx.z;
    const int tr = tile >> 3, tc = tile & 7;
    const int ti0 = tr * TI_, tj0 = tc * TJ_;

    const int tid = threadIdx.x;
    const int pix = tid >> 1;              // 0..127
    const int h   = tid & 1;               // column-half owner (v = 4h + s)
    const int ti = pix >> 4;               // 0..7
    const int tj = pix & 15;               // 0..15
    const int gi = ti0 + ti, gj = tj0 + tj;

    // ---- hoisted staging setup: thread owns elements tid and 256+tid ----
    const float LOG2E = 1.4426950408889634f;
    int   soff[2];      // clamped global offset
    float swt[2];       // in-bounds * mask * log2e
    float ozw[2];       // 0 for OOB (store zero word), 1 otherwise
    int   slds[2];      // word index in LDS
    #pragma unroll
    for (int r = 0; r < 2; ++r) {
        int e = tid + r * 256;
        bool act = (e < NELEM);
        int pr = e / PCOLS, pc = e - pr * PCOLS;
        int mi = ti0 + pr - R_, mj = tj0 + pc - R_;
        bool inb = act && mi >= 0 && mi < N_ && mj >= 0 && mj < N_;
        int cmi = mi < 0 ? 0 : (mi > N_ - 1 ? N_ - 1 : mi);
        int cmj = mj < 0 ? 0 : (mj > N_ - 1 ? N_ - 1 : mj);
        soff[r] = cmi * N_ + cmj;
        swt[r]  = inb ? ((float)mask[b * NN + soff[r]] * LOG2E) : 0.f;
        ozw[r]  = inb ? 1.f : 0.f;
        slds[r] = act ? (pr * PSTR + pc) : (PROWS * PSTR + 4);  // spare slot
    }

    // phantom kill: h=1's 4th tap is v=7 (reads REAL staged data for tj<15)
    const h2 ph2 = h ? (h2){(__fp16)1.f, (__fp16)0.f}
                     : (h2){(__fp16)1.f, (__fp16)1.f};
    const h2 one2 = (h2){(__fp16)1.f, (__fp16)1.f};
    const int cbase = (ti + R_) * PSTR + (tj + R_);  // center word
    const int bh = ti * PSTR + tj + 4 * h;           // row-u tap base (u=0)

    h2 Aacc[14];
    #pragma unroll
    for (int i = 0; i < 14; ++i) Aacc[i] = (h2){(__fp16)0.f, (__fp16)0.f};

    const int k0 = kc * KCHUNK;
    const int k1 = (k0 + KCHUNK < K_) ? (k0 + KCHUNK) : K_;
    const float* fb = feats + (size_t)b * K_ * NN;

    // zero-init all words once: pad cols 22,23 / spare slot stay 0 forever
    for (int e = tid; e < LDSP; e += 256) patchw[e] = 0u;

    // software prefetch of first k (pre = f * mask * log2e)
    const float* fk0 = fb + (size_t)k0 * NN;
    float pre0 = fk0[soff[0]] * swt[0];
    float pre1 = fk0[soff[1]] * swt[1];

    __syncthreads();

    for (int k = k0; k < k1; ++k) {
        patchw[slds[0]] = h2u(__builtin_amdgcn_cvt_pkrtz(ozw[0] * exp2f(pre0),
                                                         ozw[0] * exp2f(-pre0)));
        patchw[slds[1]] = h2u(__builtin_amdgcn_cvt_pkrtz(ozw[1] * exp2f(pre1),
                                                         ozw[1] * exp2f(-pre1)));
        // prefetch next k while this one computes
        float n0 = 0.f, n1 = 0.f;
        if (k + 1 < k1) {
            const float* fn = fb + (size_t)(k + 1) * NN;
            n0 = fn[soff[0]] * swt[0];
            n1 = fn[soff[1]] * swt[1];
        }
        __syncthreads();

        // center (E,I) broadcast into both packed lanes
        const unsigned cw = patchw[cbase];
        const h2 cE2 = u2h(__builtin_amdgcn_perm(cw, cw, 0x01000100u));
        const h2 cI2 = u2h(__builtin_amdgcn_perm(cw, cw, 0x03020302u));

        h2 ex[14];
        float dsum = 0.f;
        #pragma unroll
        for (int u = 0; u < D_; ++u) {
            const int rb = bh + u * PSTR;
            const unsigned w0 = patchw[rb];
            const unsigned w1 = patchw[rb + 1];
            const unsigned w2 = patchw[rb + 2];
            const unsigned w3 = patchw[rb + 3];
            // deinterleave (E,I) words into packed pairs
            const h2 E01 = u2h(__builtin_amdgcn_perm(w1, w0, 0x05040100u));
            const h2 I01 = u2h(__builtin_amdgcn_perm(w1, w0, 0x07060302u));
            const h2 E23 = u2h(__builtin_amdgcn_perm(w3, w2, 0x05040100u));
            const h2 I23 = u2h(__builtin_amdgcn_perm(w3, w2, 0x07060302u));
            // t = max(Ec*In^-1, En*Ic^-1) = e^|fc-fn|, two taps per op
            h2 t01 = __builtin_elementwise_max(cE2 * I01, E01 * cI2);
            h2 t23 = __builtin_elementwise_max(cE2 * I23, E23 * cI2);
            t23 = t23 * ph2;               // kill phantom v=7 (h=1 only)
            dsum = FDOT2(t01, one2, dsum);
            dsum = FDOT2(t23, one2, dsum);
            ex[u * 2]     = t01;
            ex[u * 2 + 1] = t23;
        }
        const float denom = dsum + __shfl_xor(dsum, 1, 64);  // lane pair = pixel
        const float scale = cp[k] * __frcp_rn(denom);        // denom >= 1
        const h2 s2 = __builtin_amdgcn_cvt_pkrtz(scale, scale);
        #pragma unroll
        for (int m = 0; m < 14; ++m) Aacc[m] = ex[m] * s2 + Aacc[m];
        __syncthreads();

        pre0 = n0; pre1 = n1;
    }

    if (mask[b * NN + gi * N_ + gj] != 0) {
        const int pixg = gi * N_ + gj;
        // w = u*7 + 4h + 2m (+1 for tv[1]); h=1,m=1,tv[1] = phantom v=7
        float* ab = Aout + (size_t)b * W_ * NN + pixg;
        #pragma unroll
        for (int u = 0; u < D_; ++u) {
            #pragma unroll
            for (int m = 0; m < 2; ++m) {
                const h2 tv = Aacc[u * 2 + m];
                const int wbase = u * D_ + 4 * h + 2 * m;
                atomicAdd(ab + (size_t)wbase * NN, (float)tv[0]);
                if (h == 0 || m < 1)
                    atomicAdd(ab + (size_t)(wbase + 1) * NN, (float)tv[1]);
            }
        }
    }
}

// Gather R4 (kept): tiled + LDS-staged. Block = one 8x16 q-tile (256 blocks,
// 512 thr, 4 thr/q). Stages the 14x22 x2 halo x 21c once in LDS (c-major,
// zero-filled OOB), reads A exactly once (coalesced), merges the 4 threads/q
// with a quad butterfly, stores fully coalesced via a small LDS restage.
__global__ __launch_bounds__(512) void rwn_gather(
    const float* __restrict__ Aarr,  // [B,W,NN]
    const float* __restrict__ x2,    // [B,C,NN]
    float* __restrict__ out)         // [B,NN,C]
{
    __shared__ float x2h[C_ * HCELLS];   // [c][cell], cell=pr*22+pc; 25.9KB

    const int tile = blockIdx.x;     // 0..127: 16 tile-rows x 8 tile-cols
    const int b    = blockIdx.y;
    const int tr = tile >> 3, tc = tile & 7;
    const int gi0 = tr * TI_, gj0 = tc * TJ_;

    const int tid = threadIdx.x;

    // ---- stage x2 halo (zero-filled OOB) ----
    const float* xb = x2 + (size_t)b * C_ * NN;
    for (int e = tid; e < C_ * HCELLS; e += 512) {
        const int c = e / HCELLS, cell = e - c * HCELLS;
        const int pr = cell / PCOLS, pc = cell - pr * PCOLS;
        const int mi = gi0 + pr - R_, mj = gj0 + pc - R_;
        const bool inb = (mi >= 0 && mi < N_ && mj >= 0 && mj < N_);
        const int cmi = mi < 0 ? 0 : (mi > N_ - 1 ? N_ - 1 : mi);
        const int cmj = mj < 0 ? 0 : (mj > N_ - 1 ? N_ - 1 : mj);
        x2h[e] = inb ? xb[c * NN + cmi * N_ + cmj] : 0.f;
    }
    __syncthreads();

    const int h = tid & 3;           // tap-group within quad
    const int q = tid >> 2;          // 0..127 local pixel
    const int qi = q >> 4, qj = q & 15;
    const int gi = gi0 + qi, gj = gj0 + qj;
    const float* Ab = Aarr + (size_t)b * W_ * NN;

    // ---- batch the ~13 A loads (one latency exposure) ----
    float av[13];
    int   cells[13];
    #pragma unroll
    for (int idx = 0; idx < 13; ++idx) {
        int w = h + 4 * idx;
        const float valid = (w < W_) ? 1.f : 0.f;
        if (w >= W_) w = W_ - 1;     // clamp for address safety
        const int u = w / D_, v = w - u * D_;
        const int pi = gi + R_ - u, pj = gj + R_ - v;
        const int cmi = pi < 0 ? 0 : (pi > N_ - 1 ? N_ - 1 : pi);
        const int cmj = pj < 0 ? 0 : (pj > N_ - 1 ? N_ - 1 : pj);
        av[idx]    = valid * Ab[(size_t)w * NN + cmi * N_ + cmj];
        cells[idx] = (qi + 2 * R_ - u) * PCOLS + (qj + 2 * R_ - v);
    }

    // ---- accumulate 21 channels (LDS reads: stride-1 across lanes) ----
    float acc[C_];
    #pragma unroll
    for (int c = 0; c < C_; ++c) acc[c] = 0.f;
    #pragma unroll
    for (int idx = 0; idx < 13; ++idx) {
        const float a = av[idx];
        const float* xc = x2h + cells[idx];
        #pragma unroll
        for (int c = 0; c < C_; ++c)
            acc[c] += a * xc[c * HCELLS];
    }

    // ---- quad butterfly merge ----
    #pragma unroll
    for (int c = 0; c < C_; ++c) {
        acc[c] += __shfl_xor(acc[c], 1, 64);
        acc[c] += __shfl_xor(acc[c], 2, 64);
    }

    // ---- restage to LDS, then fully coalesced store ----
    __syncthreads();                 // x2h dead; reuse as out staging
    if (h == 0) {
        float* os = x2h + q * C_;    // stride 21 words -> conflict-free
        #pragma unroll
        for (int c = 0; c < C_; ++c) os[c] = acc[c];
    }
    __syncthreads();
    for (int e = tid; e < TI_ * TJ_ * C_; e += 512) {
        const int qq = e / C_, cc = e - qq * C_;
        const int gq = (gi0 + (qq >> 4)) * N_ + gj0 + (qq & 15);
        out[((size_t)b * NN + gq) * C_ + cc] = x2h[e];
    }
}

extern "C" void kernel_launch(void* const* d_in, const int* in_sizes, int n_in,
                              void* d_out, int out_size, void* d_ws, size_t ws_size,
                              hipStream_t stream) {
    const float* feats = (const float*)d_in[0];   // [B,K,N,N]
    const float* x2    = (const float*)d_in[1];   // [B,C,NN]
    const int*   mask  = (const int*)d_in[2];     // [B,N,N]
    const float* cp    = (const float*)d_in[3];   // [K]
    float* out = (float*)d_out;

    float* Aarr = (float*)d_ws;                   // [B,W,NN] fp32
    const size_t Abytes = (size_t)B_ * W_ * NN * sizeof(float);

    (void)hipMemsetAsync(Aarr, 0, Abytes, stream);

    dim3 gridA(128, KC, B_);
    rwn_affinity<<<gridA, 256, 0, stream>>>(feats, mask, cp, Aarr);

    dim3 gridG(128, B_);
    rwn_gather<<<gridG, 512, 0, stream>>>(Aarr, x2, out);
}

// Round 6
// 138.334 us; speedup vs baseline: 1.0777x; 1.0777x over previous
//
#include <hip/hip_runtime.h>
#include <hip/hip_fp16.h>

#define R_ 3
#define D_ 7            // 2R+1
#define W_ 49
#define N_ 128
#define K_ 131
#define C_ 21
#define B_ 2
#define NN (N_ * N_)
#define TI_ 8                   // tile rows
#define TJ_ 16                  // tile cols
#define PROWS (TI_ + 2 * R_)    // 14
#define PCOLS (TJ_ + 2 * R_)    // 22
#define PSTR 24                 // LDS row stride (32-bit words)
#define NELEM (PROWS * PCOLS)   // 308 staged elements
#define LDSP (PROWS * PSTR + 8) // 344 words (spare write slot at 340)
#define KC 8                    // k-chunks per tile
#define KCHUNK ((K_ + KC - 1) / KC)    // 17
#define HCELLS (PROWS * PCOLS)  // 308 halo cells for gather
#define NSLOT 28                // 28 packed half2 words per pixel (7u x 4s)

typedef __fp16 h2 __attribute__((ext_vector_type(2)));

static __device__ __forceinline__ unsigned h2u(h2 x) { return __builtin_bit_cast(unsigned, x); }
static __device__ __forceinline__ h2 u2h(unsigned x) { return __builtin_bit_cast(h2, x); }

#if defined(__has_builtin)
#if __has_builtin(__builtin_amdgcn_fdot2)
#define FDOT2(a, b, c) __builtin_amdgcn_fdot2((a), (b), (c), false)
#endif
#endif
#ifndef FDOT2
#define FDOT2(a, b, c) ((c) + (float)(a)[0] * (float)(b)[0] + (float)(a)[1] * (float)(b)[1])
#endif

// ---------------------------------------------------------------------------
// R6: the k-loop is byte-identical to R5 (proven 73us; R1/R3/R5 falsified
// VALU-count, ILP, and LDS-op theories -- dur never moved). The one component
// never varied is the ATOMIC epilogue: 6.4M f32 atomicAdds with 8-way
// same-address contention (KC k-chunk blocks of a tile hit the same A words
// concurrently) and 2x partial-line write amplification (WRITE 50MB vs 25.7MB
// payload). R6 removes atomics + memset entirely: each (tile,kc) block PLAIN-
// STORES its packed fp16 Aacc words into a private slice Asl[kc][b][28][NN]
// (zero for unmasked pixels -> full coverage, no memset); the gather sums the
// KC slices in f32 (same math as the f32 atomic accumulation; absmax ~0.25).
// ws need = 29.4MB; host falls back to the exact R5 atomic path if ws_size
// is too small (ws-probe in that case).
// Packed word layout per pixel: slot s=2h+m (s=0..3) holds taps
// w = u*7+2s (lane0) and w+1 (lane1); lane1 of s=3 is the phantom (never
// read by gather since v<=6; its value is already zeroed in Aacc).
// ---------------------------------------------------------------------------
__global__ __launch_bounds__(256) void rwn_affinity_s(
    const float* __restrict__ feats,   // [B,K,N,N]
    const int*   __restrict__ mask,    // [B,N,N]
    const float* __restrict__ cp,      // [K]
    unsigned* __restrict__ Asl)        // [KC,B,28,NN] packed half2 slices
{
    __shared__ unsigned patchw[LDSP];  // half2(E, 1/E) per halo cell

    const int tile = blockIdx.x;           // 0..127 (16x8 tiles of 8x16)
    const int kc   = blockIdx.y;
    const int b    = blockIdx.z;
    const int tr = tile >> 3, tc = tile & 7;
    const int ti0 = tr * TI_, tj0 = tc * TJ_;

    const int tid = threadIdx.x;
    const int pix = tid >> 1;              // 0..127
    const int h   = tid & 1;               // column-half owner (v = 4h + s)
    const int ti = pix >> 4;               // 0..7
    const int tj = pix & 15;               // 0..15
    const int gi = ti0 + ti, gj = tj0 + tj;

    // ---- hoisted staging setup: thread owns elements tid and 256+tid ----
    const float LOG2E = 1.4426950408889634f;
    int   soff[2];      // clamped global offset
    float swt[2];       // in-bounds * mask * log2e
    float ozw[2];       // 0 for OOB (store zero word), 1 otherwise
    int   slds[2];      // word index in LDS
    #pragma unroll
    for (int r = 0; r < 2; ++r) {
        int e = tid + r * 256;
        bool act = (e < NELEM);
        int pr = e / PCOLS, pc = e - pr * PCOLS;
        int mi = ti0 + pr - R_, mj = tj0 + pc - R_;
        bool inb = act && mi >= 0 && mi < N_ && mj >= 0 && mj < N_;
        int cmi = mi < 0 ? 0 : (mi > N_ - 1 ? N_ - 1 : mi);
        int cmj = mj < 0 ? 0 : (mj > N_ - 1 ? N_ - 1 : mj);
        soff[r] = cmi * N_ + cmj;
        swt[r]  = inb ? ((float)mask[b * NN + soff[r]] * LOG2E) : 0.f;
        ozw[r]  = inb ? 1.f : 0.f;
        slds[r] = act ? (pr * PSTR + pc) : (PROWS * PSTR + 4);  // spare slot
    }

    // phantom kill: h=1's 4th tap lane1 is v=7 (reads REAL staged data)
    const h2 ph2 = h ? (h2){(__fp16)1.f, (__fp16)0.f}
                     : (h2){(__fp16)1.f, (__fp16)1.f};
    const h2 one2 = (h2){(__fp16)1.f, (__fp16)1.f};
    const int cbase = (ti + R_) * PSTR + (tj + R_);  // center word
    const int bh = ti * PSTR + tj + 4 * h;           // row-u tap base (u=0)

    h2 Aacc[14];
    #pragma unroll
    for (int i = 0; i < 14; ++i) Aacc[i] = (h2){(__fp16)0.f, (__fp16)0.f};

    const int k0 = kc * KCHUNK;
    const int k1 = (k0 + KCHUNK < K_) ? (k0 + KCHUNK) : K_;
    const float* fb = feats + (size_t)b * K_ * NN;

    // zero-init all words once: pad cols 22,23 / spare slot stay 0 forever
    for (int e = tid; e < LDSP; e += 256) patchw[e] = 0u;

    // software prefetch of first k (pre = f * mask * log2e)
    const float* fk0 = fb + (size_t)k0 * NN;
    float pre0 = fk0[soff[0]] * swt[0];
    float pre1 = fk0[soff[1]] * swt[1];

    __syncthreads();

    for (int k = k0; k < k1; ++k) {
        patchw[slds[0]] = h2u(__builtin_amdgcn_cvt_pkrtz(ozw[0] * exp2f(pre0),
                                                         ozw[0] * exp2f(-pre0)));
        patchw[slds[1]] = h2u(__builtin_amdgcn_cvt_pkrtz(ozw[1] * exp2f(pre1),
                                                         ozw[1] * exp2f(-pre1)));
        // prefetch next k while this one computes
        float n0 = 0.f, n1 = 0.f;
        if (k + 1 < k1) {
            const float* fn = fb + (size_t)(k + 1) * NN;
            n0 = fn[soff[0]] * swt[0];
            n1 = fn[soff[1]] * swt[1];
        }
        __syncthreads();

        // center (E,I) broadcast into both packed lanes
        const unsigned cw = patchw[cbase];
        const h2 cE2 = u2h(__builtin_amdgcn_perm(cw, cw, 0x01000100u));
        const h2 cI2 = u2h(__builtin_amdgcn_perm(cw, cw, 0x03020302u));

        h2 ex[14];
        float dsum = 0.f;
        #pragma unroll
        for (int u = 0; u < D_; ++u) {
            const int rb = bh + u * PSTR;
            const unsigned w0 = patchw[rb];
            const unsigned w1 = patchw[rb + 1];
            const unsigned w2 = patchw[rb + 2];
            const unsigned w3 = patchw[rb + 3];
            // deinterleave (E,I) words into packed pairs
            const h2 E01 = u2h(__builtin_amdgcn_perm(w1, w0, 0x05040100u));
            const h2 I01 = u2h(__builtin_amdgcn_perm(w1, w0, 0x07060302u));
            const h2 E23 = u2h(__builtin_amdgcn_perm(w3, w2, 0x05040100u));
            const h2 I23 = u2h(__builtin_amdgcn_perm(w3, w2, 0x07060302u));
            // t = max(Ec*In^-1, En*Ic^-1) = e^|fc-fn|, two taps per op
            h2 t01 = __builtin_elementwise_max(cE2 * I01, E01 * cI2);
            h2 t23 = __builtin_elementwise_max(cE2 * I23, E23 * cI2);
            t23 = t23 * ph2;               // kill phantom v=7 (h=1 only)
            dsum = FDOT2(t01, one2, dsum);
            dsum = FDOT2(t23, one2, dsum);
            ex[u * 2]     = t01;
            ex[u * 2 + 1] = t23;
        }
        const float denom = dsum + __shfl_xor(dsum, 1, 64);  // lane pair = pixel
        const float scale = cp[k] * __frcp_rn(denom);        // denom >= 1
        const h2 s2 = __builtin_amdgcn_cvt_pkrtz(scale, scale);
        #pragma unroll
        for (int m = 0; m < 14; ++m) Aacc[m] = ex[m] * s2 + Aacc[m];
        __syncthreads();

        pre0 = n0; pre1 = n1;
    }

    // ---- epilogue: PLAIN stores of packed Aacc into this kc's slice ----
    const int mk = mask[b * NN + gi * N_ + gj];
    const h2 z2 = (h2){(__fp16)0.f, (__fp16)0.f};
    const int pixg = gi * N_ + gj;
    unsigned* ab = Asl + ((size_t)(kc * B_ + b) * NSLOT) * NN + pixg;
    #pragma unroll
    for (int u = 0; u < D_; ++u) {
        #pragma unroll
        for (int m = 0; m < 2; ++m) {
            const h2 tv = mk ? Aacc[u * 2 + m] : z2;   // unmasked rows -> 0
            ab[(size_t)(u * 4 + 2 * h + m) * NN] = h2u(tv);
        }
    }
}

// Gather R6: as R4 (tiled, LDS-staged x2 halo, quad split, coalesced store)
// but reads the KC packed-fp16 slices and sums them in f32 (replaces the
// f32 atomic accumulation; same math, different order).
__global__ __launch_bounds__(512) void rwn_gather_s(
    const unsigned* __restrict__ Asl,  // [KC,B,28,NN] packed half2
    const float* __restrict__ x2,      // [B,C,NN]
    float* __restrict__ out)           // [B,NN,C]
{
    __shared__ float x2h[C_ * HCELLS];   // [c][cell], cell=pr*22+pc; 25.9KB

    const int tile = blockIdx.x;     // 0..127: 16 tile-rows x 8 tile-cols
    const int b    = blockIdx.y;
    const int tr = tile >> 3, tc = tile & 7;
    const int gi0 = tr * TI_, gj0 = tc * TJ_;

    const int tid = threadIdx.x;

    // ---- stage x2 halo (zero-filled OOB) ----
    const float* xb = x2 + (size_t)b * C_ * NN;
    for (int e = tid; e < C_ * HCELLS; e += 512) {
        const int c = e / HCELLS, cell = e - c * HCELLS;
        const int pr = cell / PCOLS, pc = cell - pr * PCOLS;
        const int mi = gi0 + pr - R_, mj = gj0 + pc - R_;
        const bool inb = (mi >= 0 && mi < N_ && mj >= 0 && mj < N_);
        const int cmi = mi < 0 ? 0 : (mi > N_ - 1 ? N_ - 1 : mi);
        const int cmj = mj < 0 ? 0 : (mj > N_ - 1 ? N_ - 1 : mj);
        x2h[e] = inb ? xb[c * NN + cmi * N_ + cmj] : 0.f;
    }
    __syncthreads();

    const int h = tid & 3;           // tap-group within quad
    const int q = tid >> 2;          // 0..127 local pixel
    const int qi = q >> 4, qj = q & 15;
    const int gi = gi0 + qi, gj = gj0 + qj;

    // ---- batch the ~13 A taps: per tap sum KC slices in f32 ----
    float av[13];
    int   cells[13];
    #pragma unroll
    for (int idx = 0; idx < 13; ++idx) {
        int w = h + 4 * idx;
        const float valid0 = (w < W_) ? 1.f : 0.f;
        if (w >= W_) w = 0;          // clamp for address safety
        const int u = w / D_, vv = w - u * D_;
        const int s = vv >> 1, ln = vv & 1;
        const int pi = gi + R_ - u, pj = gj + R_ - vv;
        const int cmi = pi < 0 ? 0 : (pi > N_ - 1 ? N_ - 1 : pi);
        const int cmj = pj < 0 ? 0 : (pj > N_ - 1 ? N_ - 1 : pj);
        const float valid = (pi >= 0 && pi < N_ && pj >= 0 && pj < N_)
                          ? valid0 : 0.f;
        const int p = cmi * N_ + cmj;
        const size_t wordoff = (size_t)(u * 4 + s) * NN + p;
        float alo = 0.f, ahi = 0.f;
        #pragma unroll
        for (int kc = 0; kc < KC; ++kc) {
            const h2 pr2 = u2h(Asl[((size_t)(kc * B_ + b) * NSLOT) * NN + wordoff]);
            alo += (float)pr2[0];
            ahi += (float)pr2[1];
        }
        av[idx]    = valid * (ln ? ahi : alo);
        cells[idx] = (qi + 2 * R_ - u) * PCOLS + (qj + 2 * R_ - vv);
    }

    // ---- accumulate 21 channels (LDS reads: stride-1 across lanes) ----
    float acc[C_];
    #pragma unroll
    for (int c = 0; c < C_; ++c) acc[c] = 0.f;
    #pragma unroll
    for (int idx = 0; idx < 13; ++idx) {
        const float a = av[idx];
        const float* xc = x2h + cells[idx];
        #pragma unroll
        for (int c = 0; c < C_; ++c)
            acc[c] += a * xc[c * HCELLS];
    }

    // ---- quad butterfly merge ----
    #pragma unroll
    for (int c = 0; c < C_; ++c) {
        acc[c] += __shfl_xor(acc[c], 1, 64);
        acc[c] += __shfl_xor(acc[c], 2, 64);
    }

    // ---- restage to LDS, then fully coalesced store ----
    __syncthreads();                 // x2h dead; reuse as out staging
    if (h == 0) {
        float* os = x2h + q * C_;    // stride 21 words -> conflict-free
        #pragma unroll
        for (int c = 0; c < C_; ++c) os[c] = acc[c];
    }
    __syncthreads();
    for (int e = tid; e < TI_ * TJ_ * C_; e += 512) {
        const int qq = e / C_, cc = e - qq * C_;
        const int gq = (gi0 + (qq >> 4)) * N_ + gj0 + (qq & 15);
        out[((size_t)b * NN + gq) * C_ + cc] = x2h[e];
    }
}

// ============================================================================
// Legacy fallback path (exact R5 kernels): used only if ws_size < 29.4 MB.
// ============================================================================
__global__ __launch_bounds__(256) void rwn_affinity_at(
    const float* __restrict__ feats, const int* __restrict__ mask,
    const float* __restrict__ cp, float* __restrict__ Aout)
{
    __shared__ unsigned patchw[LDSP];
    const int tile = blockIdx.x, kc = blockIdx.y, b = blockIdx.z;
    const int tr = tile >> 3, tc = tile & 7;
    const int ti0 = tr * TI_, tj0 = tc * TJ_;
    const int tid = threadIdx.x;
    const int pix = tid >> 1, h = tid & 1;
    const int ti = pix >> 4, tj = pix & 15;
    const int gi = ti0 + ti, gj = tj0 + tj;
    const float LOG2E = 1.4426950408889634f;
    int soff[2]; float swt[2]; float ozw[2]; int slds[2];
    #pragma unroll
    for (int r = 0; r < 2; ++r) {
        int e = tid + r * 256;
        bool act = (e < NELEM);
        int pr = e / PCOLS, pc = e - pr * PCOLS;
        int mi = ti0 + pr - R_, mj = tj0 + pc - R_;
        bool inb = act && mi >= 0 && mi < N_ && mj >= 0 && mj < N_;
        int cmi = mi < 0 ? 0 : (mi > N_ - 1 ? N_ - 1 : mi);
        int cmj = mj < 0 ? 0 : (mj > N_ - 1 ? N_ - 1 : mj);
        soff[r] = cmi * N_ + cmj;
        swt[r]  = inb ? ((float)mask[b * NN + soff[r]] * LOG2E) : 0.f;
        ozw[r]  = inb ? 1.f : 0.f;
        slds[r] = act ? (pr * PSTR + pc) : (PROWS * PSTR + 4);
    }
    const h2 ph2 = h ? (h2){(__fp16)1.f, (__fp16)0.f}
                     : (h2){(__fp16)1.f, (__fp16)1.f};
    const h2 one2 = (h2){(__fp16)1.f, (__fp16)1.f};
    const int cbase = (ti + R_) * PSTR + (tj + R_);
    const int bh = ti * PSTR + tj + 4 * h;
    h2 Aacc[14];
    #pragma unroll
    for (int i = 0; i < 14; ++i) Aacc[i] = (h2){(__fp16)0.f, (__fp16)0.f};
    const int k0 = kc * KCHUNK;
    const int k1 = (k0 + KCHUNK < K_) ? (k0 + KCHUNK) : K_;
    const float* fb = feats + (size_t)b * K_ * NN;
    for (int e = tid; e < LDSP; e += 256) patchw[e] = 0u;
    const float* fk0 = fb + (size_t)k0 * NN;
    float pre0 = fk0[soff[0]] * swt[0];
    float pre1 = fk0[soff[1]] * swt[1];
    __syncthreads();
    for (int k = k0; k < k1; ++k) {
        patchw[slds[0]] = h2u(__builtin_amdgcn_cvt_pkrtz(ozw[0] * exp2f(pre0),
                                                         ozw[0] * exp2f(-pre0)));
        patchw[slds[1]] = h2u(__builtin_amdgcn_cvt_pkrtz(ozw[1] * exp2f(pre1),
                                                         ozw[1] * exp2f(-pre1)));
        float n0 = 0.f, n1 = 0.f;
        if (k + 1 < k1) {
            const float* fn = fb + (size_t)(k + 1) * NN;
            n0 = fn[soff[0]] * swt[0];
            n1 = fn[soff[1]] * swt[1];
        }
        __syncthreads();
        const unsigned cw = patchw[cbase];
        const h2 cE2 = u2h(__builtin_amdgcn_perm(cw, cw, 0x01000100u));
        const h2 cI2 = u2h(__builtin_amdgcn_perm(cw, cw, 0x03020302u));
        h2 ex[14];
        float dsum = 0.f;
        #pragma unroll
        for (int u = 0; u < D_; ++u) {
            const int rb = bh + u * PSTR;
            const unsigned w0 = patchw[rb];
            const unsigned w1 = patchw[rb + 1];
            const unsigned w2 = patchw[rb + 2];
            const unsigned w3 = patchw[rb + 3];
            const h2 E01 = u2h(__builtin_amdgcn_perm(w1, w0, 0x05040100u));
            const h2 I01 = u2h(__builtin_amdgcn_perm(w1, w0, 0x07060302u));
            const h2 E23 = u2h(__builtin_amdgcn_perm(w3, w2, 0x05040100u));
            const h2 I23 = u2h(__builtin_amdgcn_perm(w3, w2, 0x07060302u));
            h2 t01 = __builtin_elementwise_max(cE2 * I01, E01 * cI2);
            h2 t23 = __builtin_elementwise_max(cE2 * I23, E23 * cI2);
            t23 = t23 * ph2;
            dsum = FDOT2(t01, one2, dsum);
            dsum = FDOT2(t23, one2, dsum);
            ex[u * 2]     = t01;
            ex[u * 2 + 1] = t23;
        }
        const float denom = dsum + __shfl_xor(dsum, 1, 64);
        const float scale = cp[k] * __frcp_rn(denom);
        const h2 s2 = __builtin_amdgcn_cvt_pkrtz(scale, scale);
        #pragma unroll
        for (int m = 0; m < 14; ++m) Aacc[m] = ex[m] * s2 + Aacc[m];
        __syncthreads();
        pre0 = n0; pre1 = n1;
    }
    if (mask[b * NN + gi * N_ + gj] != 0) {
        const int pixg = gi * N_ + gj;
        float* ab = Aout + (size_t)b * W_ * NN + pixg;
        #pragma unroll
        for (int u = 0; u < D_; ++u) {
            #pragma unroll
            for (int m = 0; m < 2; ++m) {
                const h2 tv = Aacc[u * 2 + m];
                const int wbase = u * D_ + 4 * h + 2 * m;
                atomicAdd(ab + (size_t)wbase * NN, (float)tv[0]);
                if (h == 0 || m < 1)
                    atomicAdd(ab + (size_t)(wbase + 1) * NN, (float)tv[1]);
            }
        }
    }
}

__global__ __launch_bounds__(512) void rwn_gather_at(
    const float* __restrict__ Aarr, const float* __restrict__ x2,
    float* __restrict__ out)
{
    __shared__ float x2h[C_ * HCELLS];
    const int tile = blockIdx.x, b = blockIdx.y;
    const int tr = tile >> 3, tc = tile & 7;
    const int gi0 = tr * TI_, gj0 = tc * TJ_;
    const int tid = threadIdx.x;
    const float* xb = x2 + (size_t)b * C_ * NN;
    for (int e = tid; e < C_ * HCELLS; e += 512) {
        const int c = e / HCELLS, cell = e - c * HCELLS;
        const int pr = cell / PCOLS, pc = cell - pr * PCOLS;
        const int mi = gi0 + pr - R_, mj = gj0 + pc - R_;
        const bool inb = (mi >= 0 && mi < N_ && mj >= 0 && mj < N_);
        const int cmi = mi < 0 ? 0 : (mi > N_ - 1 ? N_ - 1 : mi);
        const int cmj = mj < 0 ? 0 : (mj > N_ - 1 ? N_ - 1 : mj);
        x2h[e] = inb ? xb[c * NN + cmi * N_ + cmj] : 0.f;
    }
    __syncthreads();
    const int h = tid & 3;
    const int q = tid >> 2;
    const int qi = q >> 4, qj = q & 15;
    const int gi = gi0 + qi, gj = gj0 + qj;
    const float* Ab = Aarr + (size_t)b * W_ * NN;
    float av[13];
    int   cells[13];
    #pragma unroll
    for (int idx = 0; idx < 13; ++idx) {
        int w = h + 4 * idx;
        const float valid = (w < W_) ? 1.f : 0.f;
        if (w >= W_) w = W_ - 1;
        const int u = w / D_, v = w - u * D_;
        const int pi = gi + R_ - u, pj = gj + R_ - v;
        const int cmi = pi < 0 ? 0 : (pi > N_ - 1 ? N_ - 1 : pi);
        const int cmj = pj < 0 ? 0 : (pj > N_ - 1 ? N_ - 1 : pj);
        av[idx]    = valid * Ab[(size_t)w * NN + cmi * N_ + cmj];
        cells[idx] = (qi + 2 * R_ - u) * PCOLS + (qj + 2 * R_ - v);
    }
    float acc[C_];
    #pragma unroll
    for (int c = 0; c < C_; ++c) acc[c] = 0.f;
    #pragma unroll
    for (int idx = 0; idx < 13; ++idx) {
        const float a = av[idx];
        const float* xc = x2h + cells[idx];
        #pragma unroll
        for (int c = 0; c < C_; ++c)
            acc[c] += a * xc[c * HCELLS];
    }
    #pragma unroll
    for (int c = 0; c < C_; ++c) {
        acc[c] += __shfl_xor(acc[c], 1, 64);
        acc[c] += __shfl_xor(acc[c], 2, 64);
    }
    __syncthreads();
    if (h == 0) {
        float* os = x2h + q * C_;
        #pragma unroll
        for (int c = 0; c < C_; ++c) os[c] = acc[c];
    }
    __syncthreads();
    for (int e = tid; e < TI_ * TJ_ * C_; e += 512) {
        const int qq = e / C_, cc = e - qq * C_;
        const int gq = (gi0 + (qq >> 4)) * N_ + gj0 + (qq & 15);
        out[((size_t)b * NN + gq) * C_ + cc] = x2h[e];
    }
}

extern "C" void kernel_launch(void* const* d_in, const int* in_sizes, int n_in,
                              void* d_out, int out_size, void* d_ws, size_t ws_size,
                              hipStream_t stream) {
    const float* feats = (const float*)d_in[0];   // [B,K,N,N]
    const float* x2    = (const float*)d_in[1];   // [B,C,NN]
    const int*   mask  = (const int*)d_in[2];     // [B,N,N]
    const float* cp    = (const float*)d_in[3];   // [K]
    float* out = (float*)d_out;

    const size_t need = (size_t)KC * B_ * NSLOT * NN * sizeof(unsigned); // 29.4MB

    if (ws_size >= need) {
        // slices path: no atomics, no memset
        unsigned* Asl = (unsigned*)d_ws;          // [KC,B,28,NN]
        dim3 gridA(128, KC, B_);
        rwn_affinity_s<<<gridA, 256, 0, stream>>>(feats, mask, cp, Asl);
        dim3 gridG(128, B_);
        rwn_gather_s<<<gridG, 512, 0, stream>>>(Asl, x2, out);
    } else {
        // legacy R5 path (ws too small): f32 atomic accumulation
        float* Aarr = (float*)d_ws;               // [B,W,NN] fp32
        const size_t Abytes = (size_t)B_ * W_ * NN * sizeof(float);
        (void)hipMemsetAsync(Aarr, 0, Abytes, stream);
        dim3 gridA(128, KC, B_);
        rwn_affinity_at<<<gridA, 256, 0, stream>>>(feats, mask, cp, Aarr);
        dim3 gridG(128, B_);
        rwn_gather_at<<<gridG, 512, 0, stream>>>(Aarr, x2, out);
    }
}

// Round 7
// 133.089 us; speedup vs baseline: 1.1201x; 1.0394x over previous
//
#include <hip/hip_runtime.h>
#include <hip/hip_fp16.h>

#define R_ 3
#define D_ 7            // 2R+1
#define W_ 49
#define N_ 128
#define K_ 131
#define C_ 21
#define B_ 2
#define NN (N_ * N_)
#define TI_ 8                   // tile rows
#define TJ_ 16                  // tile cols
#define PROWS (TI_ + 2 * R_)    // 14
#define PCOLS (TJ_ + 2 * R_)    // 22
#define PSTR 24                 // LDS row stride (32-bit words)
#define NELEM (PROWS * PCOLS)   // 308 staged elements
#define LDSP (PROWS * PSTR + 8) // 344 words (spare write slot at 340)
#define KC 8                    // k-chunks per tile
#define KCHUNK ((K_ + KC - 1) / KC)    // 17
#define HCELLS (PROWS * PCOLS)  // 308 halo cells for gather
#define NSLOT 28                // 28 packed half2 words per pixel (7u x 4s)

typedef __fp16 h2 __attribute__((ext_vector_type(2)));

static __device__ __forceinline__ unsigned h2u(h2 x) { return __builtin_bit_cast(unsigned, x); }
static __device__ __forceinline__ h2 u2h(unsigned x) { return __builtin_bit_cast(h2, x); }

#if defined(__has_builtin)
#if __has_builtin(__builtin_amdgcn_fdot2)
#define FDOT2(a, b, c) __builtin_amdgcn_fdot2((a), (b), (c), false)
#endif
#endif
#ifndef FDOT2
#define FDOT2(a, b, c) ((c) + (float)(a)[0] * (float)(b)[0] + (float)(a)[1] * (float)(b)[1])
#endif

// ---------------------------------------------------------------------------
// R7: R6 (slices, no atomics -- matched prediction, 60us) + ONE change:
// global prefetch distance 1 -> 2. Rocprof shows FETCH ~= full amplified
// feats volume from HBM (L3 not retaining across iterations) -> per-k
// staging load is a ~900cy HBM miss, but the old prefetch was issued only
// ~1 iteration (~450cy) ahead; both barriers make the whole block eat the
// difference (the ~33% stall = VALUBusy 67%). Manual 2x unroll with NAMED
// register pairs (a*, b* -- no runtime indexing, no spill risk; same 4
// floats as before) gives a 2-iteration issue-to-use distance (~1000cy).
// Tap math / barriers / epilogue / gather byte-identical to R6.
// ---------------------------------------------------------------------------
__global__ __launch_bounds__(256) void rwn_affinity_s(
    const float* __restrict__ feats,   // [B,K,N,N]
    const int*   __restrict__ mask,    // [B,N,N]
    const float* __restrict__ cp,      // [K]
    unsigned* __restrict__ Asl)        // [KC,B,28,NN] packed half2 slices
{
    __shared__ unsigned patchw[LDSP];  // half2(E, 1/E) per halo cell

    const int tile = blockIdx.x;           // 0..127 (16x8 tiles of 8x16)
    const int kc   = blockIdx.y;
    const int b    = blockIdx.z;
    const int tr = tile >> 3, tc = tile & 7;
    const int ti0 = tr * TI_, tj0 = tc * TJ_;

    const int tid = threadIdx.x;
    const int pix = tid >> 1;              // 0..127
    const int h   = tid & 1;               // column-half owner (v = 4h + s)
    const int ti = pix >> 4;               // 0..7
    const int tj = pix & 15;               // 0..15
    const int gi = ti0 + ti, gj = tj0 + tj;

    // ---- hoisted staging setup: thread owns elements tid and 256+tid ----
    const float LOG2E = 1.4426950408889634f;
    int   soff[2];      // clamped global offset
    float swt[2];       // in-bounds * mask * log2e
    float ozw[2];       // 0 for OOB (store zero word), 1 otherwise
    int   slds[2];      // word index in LDS
    #pragma unroll
    for (int r = 0; r < 2; ++r) {
        int e = tid + r * 256;
        bool act = (e < NELEM);
        int pr = e / PCOLS, pc = e - pr * PCOLS;
        int mi = ti0 + pr - R_, mj = tj0 + pc - R_;
        bool inb = act && mi >= 0 && mi < N_ && mj >= 0 && mj < N_;
        int cmi = mi < 0 ? 0 : (mi > N_ - 1 ? N_ - 1 : mi);
        int cmj = mj < 0 ? 0 : (mj > N_ - 1 ? N_ - 1 : mj);
        soff[r] = cmi * N_ + cmj;
        swt[r]  = inb ? ((float)mask[b * NN + soff[r]] * LOG2E) : 0.f;
        ozw[r]  = inb ? 1.f : 0.f;
        slds[r] = act ? (pr * PSTR + pc) : (PROWS * PSTR + 4);  // spare slot
    }

    // phantom kill: h=1's 4th tap lane1 is v=7 (reads REAL staged data)
    const h2 ph2 = h ? (h2){(__fp16)1.f, (__fp16)0.f}
                     : (h2){(__fp16)1.f, (__fp16)1.f};
    const h2 one2 = (h2){(__fp16)1.f, (__fp16)1.f};
    const int cbase = (ti + R_) * PSTR + (tj + R_);  // center word
    const int bh = ti * PSTR + tj + 4 * h;           // row-u tap base (u=0)

    h2 Aacc[14];
    #pragma unroll
    for (int i = 0; i < 14; ++i) Aacc[i] = (h2){(__fp16)0.f, (__fp16)0.f};

    const int k0 = kc * KCHUNK;
    const int k1 = (k0 + KCHUNK < K_) ? (k0 + KCHUNK) : K_;
    const float* fb = feats + (size_t)b * K_ * NN;

    // zero-init all words once: pad cols 22,23 / spare slot stay 0 forever
    for (int e = tid; e < LDSP; e += 256) patchw[e] = 0u;

    // ---- 2-deep prologue: a* holds k0, b* holds k0+1 ----
    float a0, a1, b0 = 0.f, b1 = 0.f;
    {
        const float* f = fb + (size_t)k0 * NN;
        a0 = f[soff[0]] * swt[0];
        a1 = f[soff[1]] * swt[1];
    }
    if (k0 + 1 < k1) {
        const float* f = fb + (size_t)(k0 + 1) * NN;
        b0 = f[soff[0]] * swt[0];
        b1 = f[soff[1]] * swt[1];
    }

    __syncthreads();   // zero-init visible

    // tap body (packed fp16, identical to R5/R6)
    auto taps = [&](int k) {
        const unsigned cw = patchw[cbase];
        const h2 cE2 = u2h(__builtin_amdgcn_perm(cw, cw, 0x01000100u));
        const h2 cI2 = u2h(__builtin_amdgcn_perm(cw, cw, 0x03020302u));
        h2 ex[14];
        float dsum = 0.f;
        #pragma unroll
        for (int u = 0; u < D_; ++u) {
            const int rb = bh + u * PSTR;
            const unsigned w0 = patchw[rb];
            const unsigned w1 = patchw[rb + 1];
            const unsigned w2 = patchw[rb + 2];
            const unsigned w3 = patchw[rb + 3];
            const h2 E01 = u2h(__builtin_amdgcn_perm(w1, w0, 0x05040100u));
            const h2 I01 = u2h(__builtin_amdgcn_perm(w1, w0, 0x07060302u));
            const h2 E23 = u2h(__builtin_amdgcn_perm(w3, w2, 0x05040100u));
            const h2 I23 = u2h(__builtin_amdgcn_perm(w3, w2, 0x07060302u));
            h2 t01 = __builtin_elementwise_max(cE2 * I01, E01 * cI2);
            h2 t23 = __builtin_elementwise_max(cE2 * I23, E23 * cI2);
            t23 = t23 * ph2;               // kill phantom v=7 (h=1 only)
            dsum = FDOT2(t01, one2, dsum);
            dsum = FDOT2(t23, one2, dsum);
            ex[u * 2]     = t01;
            ex[u * 2 + 1] = t23;
        }
        const float denom = dsum + __shfl_xor(dsum, 1, 64);  // lane pair = pixel
        const float scale = cp[k] * __frcp_rn(denom);        // denom >= 1
        const h2 s2 = __builtin_amdgcn_cvt_pkrtz(scale, scale);
        #pragma unroll
        for (int m = 0; m < 14; ++m) Aacc[m] = ex[m] * s2 + Aacc[m];
    };

    int k = k0;
    for (; k + 1 < k1; k += 2) {
        // even k: store a*, refill a* with k+2 (2-iteration distance)
        patchw[slds[0]] = h2u(__builtin_amdgcn_cvt_pkrtz(ozw[0] * exp2f(a0),
                                                         ozw[0] * exp2f(-a0)));
        patchw[slds[1]] = h2u(__builtin_amdgcn_cvt_pkrtz(ozw[1] * exp2f(a1),
                                                         ozw[1] * exp2f(-a1)));
        if (k + 2 < k1) {
            const float* f = fb + (size_t)(k + 2) * NN;
            a0 = f[soff[0]] * swt[0];
            a1 = f[soff[1]] * swt[1];
        }
        __syncthreads();
        taps(k);
        __syncthreads();

        // odd k+1: store b*, refill b* with k+3
        patchw[slds[0]] = h2u(__builtin_amdgcn_cvt_pkrtz(ozw[0] * exp2f(b0),
                                                         ozw[0] * exp2f(-b0)));
        patchw[slds[1]] = h2u(__builtin_amdgcn_cvt_pkrtz(ozw[1] * exp2f(b1),
                                                         ozw[1] * exp2f(-b1)));
        if (k + 3 < k1) {
            const float* f = fb + (size_t)(k + 3) * NN;
            b0 = f[soff[0]] * swt[0];
            b1 = f[soff[1]] * swt[1];
        }
        __syncthreads();
        taps(k + 1);
        __syncthreads();
    }
    if (k < k1) {   // odd-length tail (KCHUNK=17): a* holds the last k
        patchw[slds[0]] = h2u(__builtin_amdgcn_cvt_pkrtz(ozw[0] * exp2f(a0),
                                                         ozw[0] * exp2f(-a0)));
        patchw[slds[1]] = h2u(__builtin_amdgcn_cvt_pkrtz(ozw[1] * exp2f(a1),
                                                         ozw[1] * exp2f(-a1)));
        __syncthreads();
        taps(k);
        // no trailing barrier needed
    }

    // ---- epilogue: PLAIN stores of packed Aacc into this kc's slice ----
    const int mk = mask[b * NN + gi * N_ + gj];
    const h2 z2 = (h2){(__fp16)0.f, (__fp16)0.f};
    const int pixg = gi * N_ + gj;
    unsigned* ab = Asl + ((size_t)(kc * B_ + b) * NSLOT) * NN + pixg;
    #pragma unroll
    for (int u = 0; u < D_; ++u) {
        #pragma unroll
        for (int m = 0; m < 2; ++m) {
            const h2 tv = mk ? Aacc[u * 2 + m] : z2;   // unmasked rows -> 0
            ab[(size_t)(u * 4 + 2 * h + m) * NN] = h2u(tv);
        }
    }
}

// Gather R6 (kept): tiled, LDS-staged x2 halo, quad split, coalesced store;
// reads the KC packed-fp16 slices and sums them in f32.
__global__ __launch_bounds__(512) void rwn_gather_s(
    const unsigned* __restrict__ Asl,  // [KC,B,28,NN] packed half2
    const float* __restrict__ x2,      // [B,C,NN]
    float* __restrict__ out)           // [B,NN,C]
{
    __shared__ float x2h[C_ * HCELLS];   // [c][cell], cell=pr*22+pc; 25.9KB

    const int tile = blockIdx.x;     // 0..127: 16 tile-rows x 8 tile-cols
    const int b    = blockIdx.y;
    const int tr = tile >> 3, tc = tile & 7;
    const int gi0 = tr * TI_, gj0 = tc * TJ_;

    const int tid = threadIdx.x;

    // ---- stage x2 halo (zero-filled OOB) ----
    const float* xb = x2 + (size_t)b * C_ * NN;
    for (int e = tid; e < C_ * HCELLS; e += 512) {
        const int c = e / HCELLS, cell = e - c * HCELLS;
        const int pr = cell / PCOLS, pc = cell - pr * PCOLS;
        const int mi = gi0 + pr - R_, mj = gj0 + pc - R_;
        const bool inb = (mi >= 0 && mi < N_ && mj >= 0 && mj < N_);
        const int cmi = mi < 0 ? 0 : (mi > N_ - 1 ? N_ - 1 : mi);
        const int cmj = mj < 0 ? 0 : (mj > N_ - 1 ? N_ - 1 : mj);
        x2h[e] = inb ? xb[c * NN + cmi * N_ + cmj] : 0.f;
    }
    __syncthreads();

    const int h = tid & 3;           // tap-group within quad
    const int q = tid >> 2;          // 0..127 local pixel
    const int qi = q >> 4, qj = q & 15;
    const int gi = gi0 + qi, gj = gj0 + qj;

    // ---- batch the ~13 A taps: per tap sum KC slices in f32 ----
    float av[13];
    int   cells[13];
    #pragma unroll
    for (int idx = 0; idx < 13; ++idx) {
        int w = h + 4 * idx;
        const float valid0 = (w < W_) ? 1.f : 0.f;
        if (w >= W_) w = 0;          // clamp for address safety
        const int u = w / D_, vv = w - u * D_;
        const int s = vv >> 1, ln = vv & 1;
        const int pi = gi + R_ - u, pj = gj + R_ - vv;
        const int cmi = pi < 0 ? 0 : (pi > N_ - 1 ? N_ - 1 : pi);
        const int cmj = pj < 0 ? 0 : (pj > N_ - 1 ? N_ - 1 : pj);
        const float valid = (pi >= 0 && pi < N_ && pj >= 0 && pj < N_)
                          ? valid0 : 0.f;
        const int p = cmi * N_ + cmj;
        const size_t wordoff = (size_t)(u * 4 + s) * NN + p;
        float alo = 0.f, ahi = 0.f;
        #pragma unroll
        for (int kc = 0; kc < KC; ++kc) {
            const h2 pr2 = u2h(Asl[((size_t)(kc * B_ + b) * NSLOT) * NN + wordoff]);
            alo += (float)pr2[0];
            ahi += (float)pr2[1];
        }
        av[idx]    = valid * (ln ? ahi : alo);
        cells[idx] = (qi + 2 * R_ - u) * PCOLS + (qj + 2 * R_ - vv);
    }

    // ---- accumulate 21 channels (LDS reads: stride-1 across lanes) ----
    float acc[C_];
    #pragma unroll
    for (int c = 0; c < C_; ++c) acc[c] = 0.f;
    #pragma unroll
    for (int idx = 0; idx < 13; ++idx) {
        const float a = av[idx];
        const float* xc = x2h + cells[idx];
        #pragma unroll
        for (int c = 0; c < C_; ++c)
            acc[c] += a * xc[c * HCELLS];
    }

    // ---- quad butterfly merge ----
    #pragma unroll
    for (int c = 0; c < C_; ++c) {
        acc[c] += __shfl_xor(acc[c], 1, 64);
        acc[c] += __shfl_xor(acc[c], 2, 64);
    }

    // ---- restage to LDS, then fully coalesced store ----
    __syncthreads();                 // x2h dead; reuse as out staging
    if (h == 0) {
        float* os = x2h + q * C_;    // stride 21 words -> conflict-free
        #pragma unroll
        for (int c = 0; c < C_; ++c) os[c] = acc[c];
    }
    __syncthreads();
    for (int e = tid; e < TI_ * TJ_ * C_; e += 512) {
        const int qq = e / C_, cc = e - qq * C_;
        const int gq = (gi0 + (qq >> 4)) * N_ + gj0 + (qq & 15);
        out[((size_t)b * NN + gq) * C_ + cc] = x2h[e];
    }
}

// ============================================================================
// Legacy fallback path (exact R5 kernels): used only if ws_size < 29.4 MB.
// ============================================================================
__global__ __launch_bounds__(256) void rwn_affinity_at(
    const float* __restrict__ feats, const int* __restrict__ mask,
    const float* __restrict__ cp, float* __restrict__ Aout)
{
    __shared__ unsigned patchw[LDSP];
    const int tile = blockIdx.x, kc = blockIdx.y, b = blockIdx.z;
    const int tr = tile >> 3, tc = tile & 7;
    const int ti0 = tr * TI_, tj0 = tc * TJ_;
    const int tid = threadIdx.x;
    const int pix = tid >> 1, h = tid & 1;
    const int ti = pix >> 4, tj = pix & 15;
    const int gi = ti0 + ti, gj = tj0 + tj;
    const float LOG2E = 1.4426950408889634f;
    int soff[2]; float swt[2]; float ozw[2]; int slds[2];
    #pragma unroll
    for (int r = 0; r < 2; ++r) {
        int e = tid + r * 256;
        bool act = (e < NELEM);
        int pr = e / PCOLS, pc = e - pr * PCOLS;
        int mi = ti0 + pr - R_, mj = tj0 + pc - R_;
        bool inb = act && mi >= 0 && mi < N_ && mj >= 0 && mj < N_;
        int cmi = mi < 0 ? 0 : (mi > N_ - 1 ? N_ - 1 : mi);
        int cmj = mj < 0 ? 0 : (mj > N_ - 1 ? N_ - 1 : mj);
        soff[r] = cmi * N_ + cmj;
        swt[r]  = inb ? ((float)mask[b * NN + soff[r]] * LOG2E) : 0.f;
        ozw[r]  = inb ? 1.f : 0.f;
        slds[r] = act ? (pr * PSTR + pc) : (PROWS * PSTR + 4);
    }
    const h2 ph2 = h ? (h2){(__fp16)1.f, (__fp16)0.f}
                     : (h2){(__fp16)1.f, (__fp16)1.f};
    const h2 one2 = (h2){(__fp16)1.f, (__fp16)1.f};
    const int cbase = (ti + R_) * PSTR + (tj + R_);
    const int bh = ti * PSTR + tj + 4 * h;
    h2 Aacc[14];
    #pragma unroll
    for (int i = 0; i < 14; ++i) Aacc[i] = (h2){(__fp16)0.f, (__fp16)0.f};
    const int k0 = kc * KCHUNK;
    const int k1 = (k0 + KCHUNK < K_) ? (k0 + KCHUNK) : K_;
    const float* fb = feats + (size_t)b * K_ * NN;
    for (int e = tid; e < LDSP; e += 256) patchw[e] = 0u;
    const float* fk0 = fb + (size_t)k0 * NN;
    float pre0 = fk0[soff[0]] * swt[0];
    float pre1 = fk0[soff[1]] * swt[1];
    __syncthreads();
    for (int k = k0; k < k1; ++k) {
        patchw[slds[0]] = h2u(__builtin_amdgcn_cvt_pkrtz(ozw[0] * exp2f(pre0),
                                                         ozw[0] * exp2f(-pre0)));
        patchw[slds[1]] = h2u(__builtin_amdgcn_cvt_pkrtz(ozw[1] * exp2f(pre1),
                                                         ozw[1] * exp2f(-pre1)));
        float n0 = 0.f, n1 = 0.f;
        if (k + 1 < k1) {
            const float* fn = fb + (size_t)(k + 1) * NN;
            n0 = fn[soff[0]] * swt[0];
            n1 = fn[soff[1]] * swt[1];
        }
        __syncthreads();
        const unsigned cw = patchw[cbase];
        const h2 cE2 = u2h(__builtin_amdgcn_perm(cw, cw, 0x01000100u));
        const h2 cI2 = u2h(__builtin_amdgcn_perm(cw, cw, 0x03020302u));
        h2 ex[14];
        float dsum = 0.f;
        #pragma unroll
        for (int u = 0; u < D_; ++u) {
            const int rb = bh + u * PSTR;
            const unsigned w0 = patchw[rb];
            const unsigned w1 = patchw[rb + 1];
            const unsigned w2 = patchw[rb + 2];
            const unsigned w3 = patchw[rb + 3];
            const h2 E01 = u2h(__builtin_amdgcn_perm(w1, w0, 0x05040100u));
            const h2 I01 = u2h(__builtin_amdgcn_perm(w1, w0, 0x07060302u));
            const h2 E23 = u2h(__builtin_amdgcn_perm(w3, w2, 0x05040100u));
            const h2 I23 = u2h(__builtin_amdgcn_perm(w3, w2, 0x07060302u));
            h2 t01 = __builtin_elementwise_max(cE2 * I01, E01 * cI2);
            h2 t23 = __builtin_elementwise_max(cE2 * I23, E23 * cI2);
            t23 = t23 * ph2;
            dsum = FDOT2(t01, one2, dsum);
            dsum = FDOT2(t23, one2, dsum);
            ex[u * 2]     = t01;
            ex[u * 2 + 1] = t23;
        }
        const float denom = dsum + __shfl_xor(dsum, 1, 64);
        const float scale = cp[k] * __frcp_rn(denom);
        const h2 s2 = __builtin_amdgcn_cvt_pkrtz(scale, scale);
        #pragma unroll
        for (int m = 0; m < 14; ++m) Aacc[m] = ex[m] * s2 + Aacc[m];
        __syncthreads();
        pre0 = n0; pre1 = n1;
    }
    if (mask[b * NN + gi * N_ + gj] != 0) {
        const int pixg = gi * N_ + gj;
        float* ab = Aout + (size_t)b * W_ * NN + pixg;
        #pragma unroll
        for (int u = 0; u < D_; ++u) {
            #pragma unroll
            for (int m = 0; m < 2; ++m) {
                const h2 tv = Aacc[u * 2 + m];
                const int wbase = u * D_ + 4 * h + 2 * m;
                atomicAdd(ab + (size_t)wbase * NN, (float)tv[0]);
                if (h == 0 || m < 1)
                    atomicAdd(ab + (size_t)(wbase + 1) * NN, (float)tv[1]);
            }
        }
    }
}

__global__ __launch_bounds__(512) void rwn_gather_at(
    const float* __restrict__ Aarr, const float* __restrict__ x2,
    float* __restrict__ out)
{
    __shared__ float x2h[C_ * HCELLS];
    const int tile = blockIdx.x, b = blockIdx.y;
    const int tr = tile >> 3, tc = tile & 7;
    const int gi0 = tr * TI_, gj0 = tc * TJ_;
    const int tid = threadIdx.x;
    const float* xb = x2 + (size_t)b * C_ * NN;
    for (int e = tid; e < C_ * HCELLS; e += 512) {
        const int c = e / HCELLS, cell = e - c * HCELLS;
        const int pr = cell / PCOLS, pc = cell - pr * PCOLS;
        const int mi = gi0 + pr - R_, mj = gj0 + pc - R_;
        const bool inb = (mi >= 0 && mi < N_ && mj >= 0 && mj < N_);
        const int cmi = mi < 0 ? 0 : (mi > N_ - 1 ? N_ - 1 : mi);
        const int cmj = mj < 0 ? 0 : (mj > N_ - 1 ? N_ - 1 : mj);
        x2h[e] = inb ? xb[c * NN + cmi * N_ + cmj] : 0.f;
    }
    __syncthreads();
    const int h = tid & 3;
    const int q = tid >> 2;
    const int qi = q >> 4, qj = q & 15;
    const int gi = gi0 + qi, gj = gj0 + qj;
    const float* Ab = Aarr + (size_t)b * W_ * NN;
    float av[13];
    int   cells[13];
    #pragma unroll
    for (int idx = 0; idx < 13; ++idx) {
        int w = h + 4 * idx;
        const float valid = (w < W_) ? 1.f : 0.f;
        if (w >= W_) w = W_ - 1;
        const int u = w / D_, v = w - u * D_;
        const int pi = gi + R_ - u, pj = gj + R_ - v;
        const int cmi = pi < 0 ? 0 : (pi > N_ - 1 ? N_ - 1 : pi);
        const int cmj = pj < 0 ? 0 : (pj > N_ - 1 ? N_ - 1 : pj);
        av[idx]    = valid * Ab[(size_t)w * NN + cmi * N_ + cmj];
        cells[idx] = (qi + 2 * R_ - u) * PCOLS + (qj + 2 * R_ - v);
    }
    float acc[C_];
    #pragma unroll
    for (int c = 0; c < C_; ++c) acc[c] = 0.f;
    #pragma unroll
    for (int idx = 0; idx < 13; ++idx) {
        const float a = av[idx];
        const float* xc = x2h + cells[idx];
        #pragma unroll
        for (int c = 0; c < C_; ++c)
            acc[c] += a * xc[c * HCELLS];
    }
    #pragma unroll
    for (int c = 0; c < C_; ++c) {
        acc[c] += __shfl_xor(acc[c], 1, 64);
        acc[c] += __shfl_xor(acc[c], 2, 64);
    }
    __syncthreads();
    if (h == 0) {
        float* os = x2h + q * C_;
        #pragma unroll
        for (int c = 0; c < C_; ++c) os[c] = acc[c];
    }
    __syncthreads();
    for (int e = tid; e < TI_ * TJ_ * C_; e += 512) {
        const int qq = e / C_, cc = e - qq * C_;
        const int gq = (gi0 + (qq >> 4)) * N_ + gj0 + (qq & 15);
        out[((size_t)b * NN + gq) * C_ + cc] = x2h[e];
    }
}

extern "C" void kernel_launch(void* const* d_in, const int* in_sizes, int n_in,
                              void* d_out, int out_size, void* d_ws, size_t ws_size,
                              hipStream_t stream) {
    const float* feats = (const float*)d_in[0];   // [B,K,N,N]
    const float* x2    = (const float*)d_in[1];   // [B,C,NN]
    const int*   mask  = (const int*)d_in[2];     // [B,N,N]
    const float* cp    = (const float*)d_in[3];   // [K]
    float* out = (float*)d_out;

    const size_t need = (size_t)KC * B_ * NSLOT * NN * sizeof(unsigned); // 29.4MB

    if (ws_size >= need) {
        // slices path: no atomics, no memset
        unsigned* Asl = (unsigned*)d_ws;          // [KC,B,28,NN]
        dim3 gridA(128, KC, B_);
        rwn_affinity_s<<<gridA, 256, 0, stream>>>(feats, mask, cp, Asl);
        dim3 gridG(128, B_);
        rwn_gather_s<<<gridG, 512, 0, stream>>>(Asl, x2, out);
    } else {
        // legacy R5 path (ws too small): f32 atomic accumulation
        float* Aarr = (float*)d_ws;               // [B,W,NN] fp32
        const size_t Abytes = (size_t)B_ * W_ * NN * sizeof(float);
        (void)hipMemsetAsync(Aarr, 0, Abytes, stream);
        dim3 gridA(128, KC, B_);
        rwn_affinity_at<<<gridA, 256, 0, stream>>>(feats, mask, cp, Aarr);
        dim3 gridG(128, B_);
        rwn_gather_at<<<gridG, 512, 0, stream>>>(Aarr, x2, out);
    }
}